// Round 3
// baseline (640.688 us; speedup 1.0000x reference)
//
#include <hip/hip_runtime.h>
#include <math.h>

#define N_NODES 100000
#define N_EDGES 3200000
#define F_IN    128
#define HID     16
#define NGRAPH  64

typedef int   iv4 __attribute__((ext_vector_type(4)));
typedef float fv4 __attribute__((ext_vector_type(4)));

// Workspace layout (units of 4-byte elements, 16B-aligned region starts)
#define OFF_CNT    0         // [N] int      edge counts per dst (deg-1)
#define OFF_CURSOR 100000    // [N] int      fill cursors
#define OFF_DIS    200000    // [N] f32      rsqrt(deg)
#define OFF_ROW    300000    // [N+1] int    CSR row starts
#define OFF_BSUM   400016    // [64] int     scan block sums
#define OFF_COL    400080    // [E] int      CSR col (src) indices
#define OFF_BUFA   3600080   // [N*16] f32
#define OFF_BUFB   5200080   // [N*16] f32
// total 6,800,080 elems = ~27.2 MB

// 4 edges per thread, nontemporal load of the dst half (streamed once,
// never reused -> keep it from evicting L2-resident scatter targets).
__global__ void count_k(const int* __restrict__ ei, int* __restrict__ cnt) {
    int t = blockIdx.x * blockDim.x + threadIdx.x;
    if (t * 4 >= N_EDGES) return;
    iv4 d4 = __builtin_nontemporal_load((const iv4*)(ei + N_EDGES) + t);
    atomicAdd(&cnt[d4.x], 1);
    atomicAdd(&cnt[d4.y], 1);
    atomicAdd(&cnt[d4.z], 1);
    atomicAdd(&cnt[d4.w], 1);
}

__global__ void dis_k(const int* __restrict__ cnt, float* __restrict__ dis) {
    int i = blockIdx.x * blockDim.x + threadIdx.x;
    if (i < N_NODES) dis[i] = rsqrtf((float)cnt[i] + 1.0f);
}

// ---- 3-kernel exclusive scan of cnt[N] -> row_start[N] (+ bsum totals) ----
__global__ void scan1_k(const int* __restrict__ cnt, int* __restrict__ out,
                        int* __restrict__ bsum) {
    __shared__ int warpSums[4];
    int base = blockIdx.x * 2048 + threadIdx.x * 8;
    int v[8];
    int s = 0;
#pragma unroll
    for (int t = 0; t < 8; ++t) {
        int i = base + t;
        v[t] = (i < N_NODES) ? cnt[i] : 0;
        s += v[t];
    }
    int lane = threadIdx.x & 63, wid = threadIdx.x >> 6;
    int sc = s;
#pragma unroll
    for (int d = 1; d < 64; d <<= 1) {
        int o = __shfl_up(sc, d);
        if (lane >= d) sc += o;
    }
    if (lane == 63) warpSums[wid] = sc;
    __syncthreads();
    int wOff = 0;
    for (int w = 0; w < wid; ++w) wOff += warpSums[w];
    int excl = wOff + sc - s;
#pragma unroll
    for (int t = 0; t < 8; ++t) {
        int i = base + t;
        if (i < N_NODES) out[i] = excl;
        excl += v[t];
    }
    if (threadIdx.x == 255) bsum[blockIdx.x] = wOff + sc;
}

__global__ void scan2_k(int* __restrict__ bsum, int nb) {
    int lane = threadIdx.x;
    int v = (lane < nb) ? bsum[lane] : 0;
    int sc = v;
#pragma unroll
    for (int d = 1; d < 64; d <<= 1) {
        int o = __shfl_up(sc, d);
        if (lane >= d) sc += o;
    }
    if (lane < nb) bsum[lane] = sc - v;  // exclusive
}

__global__ void scan3_k(int* __restrict__ row_start, const int* __restrict__ bsum) {
    int i = blockIdx.x * blockDim.x + threadIdx.x;
    if (i < N_NODES) row_start[i] += bsum[i >> 11];
    if (i == 0) row_start[N_NODES] = N_EDGES;
}

// 4 edges per thread; nontemporal loads of both src and dst halves.
// The scattered col[] stores stay CACHED: col (12.8 MB) must live in L2 so
// each 64B line absorbs its ~16 partial writes (round-1 counter evidence:
// 197 MB WRITE_SIZE = 15x amplification when ei streaming evicted it).
__global__ void fill_k(const int* __restrict__ ei, const int* __restrict__ row_start,
                       int* __restrict__ cursor, int* __restrict__ col) {
    int t = blockIdx.x * blockDim.x + threadIdx.x;
    if (t * 4 >= N_EDGES) return;
    iv4 s4 = __builtin_nontemporal_load((const iv4*)(ei) + t);
    iv4 d4 = __builtin_nontemporal_load((const iv4*)(ei + N_EDGES) + t);
    {
        int pos = atomicAdd(&cursor[d4.x], 1);
        col[row_start[d4.x] + pos] = s4.x;
    }
    {
        int pos = atomicAdd(&cursor[d4.y], 1);
        col[row_start[d4.y] + pos] = s4.y;
    }
    {
        int pos = atomicAdd(&cursor[d4.z], 1);
        col[row_start[d4.z] + pos] = s4.z;
    }
    {
        int pos = atomicAdd(&cursor[d4.w], 1);
        col[row_start[d4.w] + pos] = s4.w;
    }
}

// ---- h = x @ W1   (x: [N,128], W1: [128,16]) ----
__global__ void transform1_k(const float* __restrict__ x, const float* __restrict__ W,
                             float* __restrict__ out) {
    int i = blockIdx.x * blockDim.x + threadIdx.x;
    if (i >= N_NODES) return;
    const fv4* xr = (const fv4*)(x + (size_t)i * F_IN);
    float acc[16];
#pragma unroll
    for (int j = 0; j < 16; ++j) acc[j] = 0.f;
#pragma unroll 4
    for (int k4 = 0; k4 < F_IN / 4; ++k4) {
        fv4 xv = __builtin_nontemporal_load(xr + k4);  // x streamed once
#pragma unroll
        for (int kk = 0; kk < 4; ++kk) {
            int k = k4 * 4 + kk;
            float xk = xv[kk];
#pragma unroll
            for (int j = 0; j < 16; ++j)
                acc[j] = fmaf(xk, W[k * 16 + j], acc[j]);  // W idx uniform -> s_load
        }
    }
    fv4* o = (fv4*)(out + (size_t)i * 16);
#pragma unroll
    for (int q = 0; q < 4; ++q) {
        fv4 t = { acc[q * 4], acc[q * 4 + 1], acc[q * 4 + 2], acc[q * 4 + 3] };
        o[q] = t;
    }
}

// ---- h = hin @ W2  (hin: [N,16], W2: [16,16]) ----
__global__ void transform2_k(const float* __restrict__ h, const float* __restrict__ W,
                             float* __restrict__ out) {
    int i = blockIdx.x * blockDim.x + threadIdx.x;
    if (i >= N_NODES) return;
    const fv4* hr = (const fv4*)(h + (size_t)i * 16);
    float hv[16];
#pragma unroll
    for (int q = 0; q < 4; ++q) {
        fv4 t = hr[q];
        hv[q * 4 + 0] = t.x; hv[q * 4 + 1] = t.y; hv[q * 4 + 2] = t.z; hv[q * 4 + 3] = t.w;
    }
    float acc[16];
#pragma unroll
    for (int j = 0; j < 16; ++j) acc[j] = 0.f;
#pragma unroll
    for (int k = 0; k < 16; ++k) {
#pragma unroll
        for (int j = 0; j < 16; ++j)
            acc[j] = fmaf(hv[k], W[k * 16 + j], acc[j]);
    }
    fv4* o = (fv4*)(out + (size_t)i * 16);
#pragma unroll
    for (int q = 0; q < 4; ++q) {
        fv4 t = { acc[q * 4], acc[q * 4 + 1], acc[q * 4 + 2], acc[q * 4 + 3] };
        o[q] = t;
    }
}

// ---- propagate: hout[i] = relu(dis[i]*sum_e dis[src]*hin[src] + dis[i]^2*hin[i] + b)
// 16 lanes per node (j = lane&15): h[src] line read is one coalesced 64B txn.
// col is streamed once -> nontemporal, so hin (6.4 MB) stays L2-resident.
__global__ void propagate_k(const float* __restrict__ hin, const float* __restrict__ dis,
                            const int* __restrict__ row_start, const int* __restrict__ col,
                            const float* __restrict__ bias, float* __restrict__ hout) {
    int gid = blockIdx.x * blockDim.x + threadIdx.x;
    int node = gid >> 4;
    int j = gid & 15;
    if (node >= N_NODES) return;
    int e0 = row_start[node];
    int e1 = row_start[node + 1];
    float acc = 0.f;
    for (int e = e0; e < e1; ++e) {
        int s = __builtin_nontemporal_load(col + e);
        acc = fmaf(dis[s], hin[s * 16 + j], acc);
    }
    float di = dis[node];
    float v = fmaf(di, acc, fmaf(di * di, hin[node * 16 + j], bias[j]));
    hout[node * 16 + j] = fmaxf(v, 0.f);
}

// ---- pool per graph (batch sorted) + sigmoid(pooled @ fc_w + fc_b) ----
__global__ void pool_k(const float* __restrict__ h2, const int* __restrict__ batch,
                       const float* __restrict__ fcw, const float* __restrict__ fcb,
                       float* __restrict__ out) {
    __shared__ float partial[16][16];
    int g = blockIdx.x;
    int lane16 = threadIdx.x & 15, grp = threadIdx.x >> 4;
    // lower_bound(batch, g) and lower_bound(batch, g+1)
    int lo = 0, hi = N_NODES;
    while (lo < hi) { int m = (lo + hi) >> 1; if (batch[m] < g) lo = m + 1; else hi = m; }
    int start = lo;
    lo = start; hi = N_NODES;
    while (lo < hi) { int m = (lo + hi) >> 1; if (batch[m] < g + 1) lo = m + 1; else hi = m; }
    int end = lo;
    float acc = 0.f;
    for (int i = start + grp; i < end; i += 16) acc += h2[i * 16 + lane16];
    partial[grp][lane16] = acc;
    __syncthreads();
    if (threadIdx.x < 16) {
        float s = 0.f;
#pragma unroll
        for (int gg = 0; gg < 16; ++gg) s += partial[gg][threadIdx.x];
        partial[0][threadIdx.x] = s * fcw[threadIdx.x];
    }
    __syncthreads();
    if (threadIdx.x == 0) {
        float z = fcb[0];
#pragma unroll
        for (int j = 0; j < 16; ++j) z += partial[0][j];
        out[g] = 1.0f / (1.0f + expf(-z));
    }
}

extern "C" void kernel_launch(void* const* d_in, const int* in_sizes, int n_in,
                              void* d_out, int out_size, void* d_ws, size_t ws_size,
                              hipStream_t stream) {
    const float* x    = (const float*)d_in[0];
    const int*   ei   = (const int*)d_in[1];
    const int*   batch= (const int*)d_in[2];
    const float* W1   = (const float*)d_in[3];
    const float* b1   = (const float*)d_in[4];
    const float* W2   = (const float*)d_in[5];
    const float* b2   = (const float*)d_in[6];
    const float* fcw  = (const float*)d_in[7];
    const float* fcb  = (const float*)d_in[8];
    float* out = (float*)d_out;

    float* ws = (float*)d_ws;
    int*   cnt      = (int*)(ws + OFF_CNT);
    int*   cursor   = (int*)(ws + OFF_CURSOR);
    float* dis      = ws + OFF_DIS;
    int*   row_start= (int*)(ws + OFF_ROW);
    int*   bsum     = (int*)(ws + OFF_BSUM);
    int*   col      = (int*)(ws + OFF_COL);
    float* bufA     = ws + OFF_BUFA;
    float* bufB     = ws + OFF_BUFB;

    // zero cnt + cursor (adjacent)
    (void)hipMemsetAsync(cnt, 0, (size_t)2 * N_NODES * sizeof(int), stream);

    const int B = 256;
    int gE4 = (N_EDGES / 4 + B - 1) / B;  // 3125
    int gN = (N_NODES + B - 1) / B;       // 391
    int gNH = (N_NODES * 16 + B - 1) / B; // 6250
    int nbScan = (N_NODES + 2047) / 2048; // 49

    count_k<<<gE4, B, 0, stream>>>(ei, cnt);
    dis_k<<<gN, B, 0, stream>>>(cnt, dis);
    scan1_k<<<nbScan, B, 0, stream>>>(cnt, row_start, bsum);
    scan2_k<<<1, 64, 0, stream>>>(bsum, nbScan);
    scan3_k<<<gN, B, 0, stream>>>(row_start, bsum);
    fill_k<<<gE4, B, 0, stream>>>(ei, row_start, cursor, col);

    transform1_k<<<gN, B, 0, stream>>>(x, W1, bufA);
    propagate_k<<<gNH, B, 0, stream>>>(bufA, dis, row_start, col, b1, bufB);
    transform2_k<<<gN, B, 0, stream>>>(bufB, W2, bufA);
    propagate_k<<<gNH, B, 0, stream>>>(bufA, dis, row_start, col, b2, bufB);
    pool_k<<<NGRAPH, B, 0, stream>>>(bufB, batch, fcw, fcb, out);
}

// Round 4
// 545.704 us; speedup vs baseline: 1.1741x; 1.1741x over previous
//
#include <hip/hip_runtime.h>
#include <math.h>

#define N_NODES 100000
#define N_EDGES 3200000
#define F_IN    128
#define HID     16
#define NGRAPH  64

typedef int   iv4 __attribute__((ext_vector_type(4)));
typedef float fv4 __attribute__((ext_vector_type(4)));

// ---- dst-binning params ----
#define NB        16       // buckets; bucket b covers nodes [b*6250, (b+1)*6250)
#define BWIDTH    6250
#define BIN_CAP   220000   // expected 200000 +- 433 (binomial); +46 sigma
#define EPB       2048     // edges per bin_k block

// Workspace layout (4-byte elements; binned aliases bufA region, dead before
// transform1 writes it)
#define OFF_CNT    0         // [N] int
#define OFF_CURSOR 100000    // [N] int
#define OFF_DIS    200000    // [N] f32
#define OFF_ROW    300000    // [N+1] int
#define OFF_BSUM   400016    // [64] int
#define OFF_BINCUR 400080    // [16] int
#define OFF_COL    400096    // [E] int
#define OFF_BUFA   3600096   // [N*16] f32  (aliased: binned [NB*BIN_CAP] int)
#define OFF_BUFB   5200096   // [N*16] f32
// end = 3600096 + 3520000 = 7,120,096 elems = 28.5 MB

__global__ void count_k(const int* __restrict__ ei, int* __restrict__ cnt) {
    int t = blockIdx.x * blockDim.x + threadIdx.x;
    if (t * 4 >= N_EDGES) return;
    iv4 d4 = __builtin_nontemporal_load((const iv4*)(ei + N_EDGES) + t);
    atomicAdd(&cnt[d4.x], 1);
    atomicAdd(&cnt[d4.y], 1);
    atomicAdd(&cnt[d4.z], 1);
    atomicAdd(&cnt[d4.w], 1);
}

__global__ void dis_k(const int* __restrict__ cnt, float* __restrict__ dis) {
    int i = blockIdx.x * blockDim.x + threadIdx.x;
    if (i < N_NODES) dis[i] = rsqrtf((float)cnt[i] + 1.0f);
}

// ---- 3-kernel exclusive scan of cnt[N] -> row_start[N] ----
__global__ void scan1_k(const int* __restrict__ cnt, int* __restrict__ out,
                        int* __restrict__ bsum) {
    __shared__ int warpSums[4];
    int base = blockIdx.x * 2048 + threadIdx.x * 8;
    int v[8];
    int s = 0;
#pragma unroll
    for (int t = 0; t < 8; ++t) {
        int i = base + t;
        v[t] = (i < N_NODES) ? cnt[i] : 0;
        s += v[t];
    }
    int lane = threadIdx.x & 63, wid = threadIdx.x >> 6;
    int sc = s;
#pragma unroll
    for (int d = 1; d < 64; d <<= 1) {
        int o = __shfl_up(sc, d);
        if (lane >= d) sc += o;
    }
    if (lane == 63) warpSums[wid] = sc;
    __syncthreads();
    int wOff = 0;
    for (int w = 0; w < wid; ++w) wOff += warpSums[w];
    int excl = wOff + sc - s;
#pragma unroll
    for (int t = 0; t < 8; ++t) {
        int i = base + t;
        if (i < N_NODES) out[i] = excl;
        excl += v[t];
    }
    if (threadIdx.x == 255) bsum[blockIdx.x] = wOff + sc;
}

__global__ void scan2_k(int* __restrict__ bsum, int nb) {
    int lane = threadIdx.x;
    int v = (lane < nb) ? bsum[lane] : 0;
    int sc = v;
#pragma unroll
    for (int d = 1; d < 64; d <<= 1) {
        int o = __shfl_up(sc, d);
        if (lane >= d) sc += o;
    }
    if (lane < nb) bsum[lane] = sc - v;  // exclusive
}

__global__ void scan3_k(int* __restrict__ row_start, const int* __restrict__ bsum) {
    int i = blockIdx.x * blockDim.x + threadIdx.x;
    if (i < N_NODES) row_start[i] += bsum[i >> 11];
    if (i == 0) row_start[N_NODES] = N_EDGES;
}

// ---- pass A: bin edges by dst range; block-contiguous coalesced writes ----
__global__ void bin_k(const int* __restrict__ ei, int* __restrict__ binCursor,
                      int* __restrict__ binned) {
    __shared__ int cntL[NB], cnt2[NB], segBase[NB + 1], gbase[NB];
    __shared__ int ldsOut[EPB];
    int tid = threadIdx.x;
    if (tid < NB) { cntL[tid] = 0; cnt2[tid] = 0; }
    __syncthreads();
    int myBase = blockIdx.x * EPB + tid * 8;
    bool act = (myBase < N_EDGES);   // when active, all 8 edges valid (E%8==0, EPB%8==0)
    int s[8], d[8];
    if (act) {
        const iv4* sp = (const iv4*)(ei + myBase);
        const iv4* dp = (const iv4*)(ei + N_EDGES + myBase);
        iv4 a = __builtin_nontemporal_load(sp);
        iv4 b = __builtin_nontemporal_load(sp + 1);
        iv4 c = __builtin_nontemporal_load(dp);
        iv4 e = __builtin_nontemporal_load(dp + 1);
        s[0]=a.x; s[1]=a.y; s[2]=a.z; s[3]=a.w; s[4]=b.x; s[5]=b.y; s[6]=b.z; s[7]=b.w;
        d[0]=c.x; d[1]=c.y; d[2]=c.z; d[3]=c.w; d[4]=e.x; d[5]=e.y; d[6]=e.z; d[7]=e.w;
#pragma unroll
        for (int k = 0; k < 8; ++k)
            atomicAdd(&cntL[(unsigned)d[k] / BWIDTH], 1);
    }
    __syncthreads();
    if (tid == 0) {
        int acc = 0;
#pragma unroll
        for (int b = 0; b < NB; ++b) { segBase[b] = acc; acc += cntL[b]; }
        segBase[NB] = acc;
    }
    __syncthreads();
    if (tid < NB) gbase[tid] = atomicAdd(&binCursor[tid], cntL[tid]);
    if (act) {
#pragma unroll
        for (int k = 0; k < 8; ++k) {
            int b = (unsigned)d[k] / BWIDTH;
            int off = segBase[b] + atomicAdd(&cnt2[b], 1);
            ldsOut[off] = ((d[k] - b * BWIDTH) << 17) | s[k];
        }
    }
    __syncthreads();
    for (int b = 0; b < NB; ++b) {
        int s0 = segBase[b], n = segBase[b + 1] - s0;
        int* dstp = binned + (size_t)b * BIN_CAP + gbase[b];
        for (int i = tid; i < n; i += 256)
            dstp[i] = ldsOut[s0 + i];
    }
}

// ---- pass B: per-bucket scatter into col. blockIdx = chunk*16 + bucket so
// bucket b's 128 blocks land on XCD b&7 (round-robin dispatch) -> per-XCD L2
// scatter footprint ~2 buckets * 880KB < 4MiB -> partial writes coalesce.
__global__ void scatter_k(const int* __restrict__ binCursor, const int* __restrict__ binned,
                          const int* __restrict__ row_start, int* __restrict__ cursor,
                          int* __restrict__ col) {
    int b = blockIdx.x & (NB - 1);
    int chunk = blockIdx.x >> 4;           // 128 chunks per bucket
    int n = binCursor[b];
    int per = (n + 127) >> 7;
    int lo = chunk * per;
    int hi = min(lo + per, n);
    const int* bb = binned + (size_t)b * BIN_CAP;
    for (int i = lo + threadIdx.x; i < hi; i += 256) {
        int p = __builtin_nontemporal_load(bb + i);
        int srcN = p & 0x1FFFF;
        int dst = b * BWIDTH + (p >> 17);
        int pos = atomicAdd(&cursor[dst], 1);
        col[row_start[dst] + pos] = srcN;
    }
}

// ---- h = x @ W1   (x: [N,128], W1: [128,16]) ----
__global__ void transform1_k(const float* __restrict__ x, const float* __restrict__ W,
                             float* __restrict__ out) {
    int i = blockIdx.x * blockDim.x + threadIdx.x;
    if (i >= N_NODES) return;
    const fv4* xr = (const fv4*)(x + (size_t)i * F_IN);
    float acc[16];
#pragma unroll
    for (int j = 0; j < 16; ++j) acc[j] = 0.f;
#pragma unroll 4
    for (int k4 = 0; k4 < F_IN / 4; ++k4) {
        fv4 xv = xr[k4];                 // plain load: 512B lane stride needs L1 line reuse
#pragma unroll
        for (int kk = 0; kk < 4; ++kk) {
            int k = k4 * 4 + kk;
            float xk = xv[kk];
#pragma unroll
            for (int j = 0; j < 16; ++j)
                acc[j] = fmaf(xk, W[k * 16 + j], acc[j]);
        }
    }
    fv4* o = (fv4*)(out + (size_t)i * 16);
#pragma unroll
    for (int q = 0; q < 4; ++q) {
        fv4 t = { acc[q * 4], acc[q * 4 + 1], acc[q * 4 + 2], acc[q * 4 + 3] };
        o[q] = t;
    }
}

// ---- h = hin @ W2  (hin: [N,16], W2: [16,16]) ----
__global__ void transform2_k(const float* __restrict__ h, const float* __restrict__ W,
                             float* __restrict__ out) {
    int i = blockIdx.x * blockDim.x + threadIdx.x;
    if (i >= N_NODES) return;
    const fv4* hr = (const fv4*)(h + (size_t)i * 16);
    float hv[16];
#pragma unroll
    for (int q = 0; q < 4; ++q) {
        fv4 t = hr[q];
        hv[q * 4 + 0] = t.x; hv[q * 4 + 1] = t.y; hv[q * 4 + 2] = t.z; hv[q * 4 + 3] = t.w;
    }
    float acc[16];
#pragma unroll
    for (int j = 0; j < 16; ++j) acc[j] = 0.f;
#pragma unroll
    for (int k = 0; k < 16; ++k) {
#pragma unroll
        for (int j = 0; j < 16; ++j)
            acc[j] = fmaf(hv[k], W[k * 16 + j], acc[j]);
    }
    fv4* o = (fv4*)(out + (size_t)i * 16);
#pragma unroll
    for (int q = 0; q < 4; ++q) {
        fv4 t = { acc[q * 4], acc[q * 4 + 1], acc[q * 4 + 2], acc[q * 4 + 3] };
        o[q] = t;
    }
}

// ---- propagate: hout[i] = relu(dis[i]*sum dis[src]*hin[src] + dis[i]^2*hin[i] + b)
// 16 lanes per node; col/h reads are plain (L2-cached; col read-amp absorbed in L2).
__global__ void propagate_k(const float* __restrict__ hin, const float* __restrict__ dis,
                            const int* __restrict__ row_start, const int* __restrict__ col,
                            const float* __restrict__ bias, float* __restrict__ hout) {
    int gid = blockIdx.x * blockDim.x + threadIdx.x;
    int node = gid >> 4;
    int j = gid & 15;
    if (node >= N_NODES) return;
    int e0 = row_start[node];
    int e1 = row_start[node + 1];
    float acc = 0.f;
    for (int e = e0; e < e1; ++e) {
        int s = col[e];
        acc = fmaf(dis[s], hin[s * 16 + j], acc);
    }
    float di = dis[node];
    float v = fmaf(di, acc, fmaf(di * di, hin[node * 16 + j], bias[j]));
    hout[node * 16 + j] = fmaxf(v, 0.f);
}

// ---- pool per graph (batch sorted) + sigmoid(pooled @ fc_w + fc_b) ----
__global__ void pool_k(const float* __restrict__ h2, const int* __restrict__ batch,
                       const float* __restrict__ fcw, const float* __restrict__ fcb,
                       float* __restrict__ out) {
    __shared__ float partial[16][16];
    int g = blockIdx.x;
    int lane16 = threadIdx.x & 15, grp = threadIdx.x >> 4;
    int lo = 0, hi = N_NODES;
    while (lo < hi) { int m = (lo + hi) >> 1; if (batch[m] < g) lo = m + 1; else hi = m; }
    int start = lo;
    lo = start; hi = N_NODES;
    while (lo < hi) { int m = (lo + hi) >> 1; if (batch[m] < g + 1) lo = m + 1; else hi = m; }
    int end = lo;
    float acc = 0.f;
    for (int i = start + grp; i < end; i += 16) acc += h2[i * 16 + lane16];
    partial[grp][lane16] = acc;
    __syncthreads();
    if (threadIdx.x < 16) {
        float s = 0.f;
#pragma unroll
        for (int gg = 0; gg < 16; ++gg) s += partial[gg][threadIdx.x];
        partial[0][threadIdx.x] = s * fcw[threadIdx.x];
    }
    __syncthreads();
    if (threadIdx.x == 0) {
        float z = fcb[0];
#pragma unroll
        for (int j = 0; j < 16; ++j) z += partial[0][j];
        out[g] = 1.0f / (1.0f + expf(-z));
    }
}

extern "C" void kernel_launch(void* const* d_in, const int* in_sizes, int n_in,
                              void* d_out, int out_size, void* d_ws, size_t ws_size,
                              hipStream_t stream) {
    const float* x    = (const float*)d_in[0];
    const int*   ei   = (const int*)d_in[1];
    const int*   batch= (const int*)d_in[2];
    const float* W1   = (const float*)d_in[3];
    const float* b1   = (const float*)d_in[4];
    const float* W2   = (const float*)d_in[5];
    const float* b2   = (const float*)d_in[6];
    const float* fcw  = (const float*)d_in[7];
    const float* fcb  = (const float*)d_in[8];
    float* out = (float*)d_out;

    float* ws = (float*)d_ws;
    int*   cnt      = (int*)(ws + OFF_CNT);
    int*   cursor   = (int*)(ws + OFF_CURSOR);
    float* dis      = ws + OFF_DIS;
    int*   row_start= (int*)(ws + OFF_ROW);
    int*   bsum     = (int*)(ws + OFF_BSUM);
    int*   binCur   = (int*)(ws + OFF_BINCUR);
    int*   col      = (int*)(ws + OFF_COL);
    float* bufA     = ws + OFF_BUFA;
    float* bufB     = ws + OFF_BUFB;
    int*   binned   = (int*)(ws + OFF_BUFA);   // aliased; dead before bufA written

    (void)hipMemsetAsync(cnt, 0, (size_t)2 * N_NODES * sizeof(int), stream);
    (void)hipMemsetAsync(binCur, 0, NB * sizeof(int), stream);

    const int B = 256;
    int gE4 = (N_EDGES / 4 + B - 1) / B;     // 3125
    int gN = (N_NODES + B - 1) / B;          // 391
    int gNH = (N_NODES * 16 + B - 1) / B;    // 6250
    int nbScan = (N_NODES + 2047) / 2048;    // 49
    int gBin = (N_EDGES + EPB - 1) / EPB;    // 1563

    count_k<<<gE4, B, 0, stream>>>(ei, cnt);
    dis_k<<<gN, B, 0, stream>>>(cnt, dis);
    scan1_k<<<nbScan, B, 0, stream>>>(cnt, row_start, bsum);
    scan2_k<<<1, 64, 0, stream>>>(bsum, nbScan);
    scan3_k<<<gN, B, 0, stream>>>(row_start, bsum);
    bin_k<<<gBin, B, 0, stream>>>(ei, binCur, binned);
    scatter_k<<<NB * 128, B, 0, stream>>>(binCur, binned, row_start, cursor, col);

    transform1_k<<<gN, B, 0, stream>>>(x, W1, bufA);
    propagate_k<<<gNH, B, 0, stream>>>(bufA, dis, row_start, col, b1, bufB);
    transform2_k<<<gN, B, 0, stream>>>(bufB, W2, bufA);
    propagate_k<<<gNH, B, 0, stream>>>(bufA, dis, row_start, col, b2, bufB);
    pool_k<<<NGRAPH, B, 0, stream>>>(bufB, batch, fcw, fcb, out);
}